// Round 4
// baseline (651.321 us; speedup 1.0000x reference)
//
#include <hip/hip_runtime.h>
#include <hip/hip_cooperative_groups.h>

namespace cg = cooperative_groups;

// Firefly optimizer, round 4: single persistent cooperative kernel.
// R3 post-mortem: all 9 dispatches sum to ~30-50us of work; ~110us was
// inter-dispatch overhead (~12us each even under graph replay). Fuse
// init + 4x(pair, update) into one launch with grid.sync() between phases.
// Pair math unchanged from R3: one v_mfma_f32_32x32x16_bf16 per 32x32 tile,
// gate max16(D) > sqj/2 (D = g + (T-sqi)/2), rare exact-fp32 slow path with
// atomicAdd into attr[].

#define SPECIES 4
#define POP     4096
#define DIM     16
#define NSI     (SPECIES * POP)
#define T_CUT   10.0f
#define GRID    512
#define BLOCK   256
#define GSIZE   (GRID * BLOCK)          // 131072 threads = NSI*DIM/2
#define NWAVES  (GSIZE / 64)            // 2048
#define JSPAN   (POP / 4)               // 1024 j's per pair job
// pair jobs: (s, i-tile 0..127, j-quarter 0..3) = 4*128*4 = 2048 = NWAVES

typedef __attribute__((ext_vector_type(8)))  short short8;    // 8 bf16
typedef __attribute__((ext_vector_type(16))) float floatx16;  // MFMA C/D

__device__ __forceinline__ unsigned short f2bf(float f) {
    unsigned u = __float_as_uint(f);
    u += 0x7FFFu + ((u >> 16) & 1u);
    return (unsigned short)(u >> 16);
}

__device__ __forceinline__ float seg16_sum(float v) {
    v += __shfl_xor(v, 1, 16);
    v += __shfl_xor(v, 2, 16);
    v += __shfl_xor(v, 4, 16);
    v += __shfl_xor(v, 8, 16);
    return v;
}

__global__ __launch_bounds__(BLOCK, 2) void mega_kernel(
        const float* __restrict__ x0,
        const float* __restrict__ noise,
        int steps,
        float* __restrict__ out,
        float* __restrict__ xA, float* __restrict__ xB,
        float* __restrict__ attr,
        float* __restrict__ sq, float* __restrict__ cost,
        unsigned short* __restrict__ xb) {
    cg::grid_group grid = cg::this_grid();
    const int gid   = blockIdx.x * BLOCK + threadIdx.x;
    const int lane  = threadIdx.x & 63;
    const int wgid  = gid >> 6;                 // global wave id, 0..2047
    const int l31   = lane & 31;
    const int half  = lane >> 5;

    // ---- init: x0 -> xb/sq/cost, zero attr --------------------------------
    for (int t = gid; t < NSI * DIM; t += GSIZE) {
        int si = t >> 4, d = t & 15;
        attr[t] = 0.0f;
        float xv = x0[t];
        xb[t] = f2bf(xv);
        float s1t = seg16_sum(xv * xv);
        float ct  = seg16_sum(cospif(2.0f * xv));
        if (d == 0) {
            sq[si]   = s1t;
            cost[si] = 10.0f * DIM + s1t - 10.0f * ct;
        }
    }
    grid.sync();

    const float* xin = x0;
    float alpha = 0.1f;
    for (int step = 0; step < steps; ++step) {
        // ---- pair phase: one job per wave ---------------------------------
        {
            const int jc = wgid & 3;
            const int it = (wgid >> 2) & 127;
            const int s  = wgid >> 9;
            const int sb = s * POP;
            const int i0 = it * 32;
            const int j0 = jc * JSPAN;

            const short8* ap = (const short8*)(xb + (size_t)(sb + i0) * DIM);
            const short8  afrag = ap[(l31 << 1) | half];

            floatx16 c;   // loop-invariant: row r = (r&3) + 8*(r>>2) + 4*half
            {
                const float* sqi = sq + sb + i0 + 4 * half;
                #pragma unroll
                for (int b = 0; b < 4; ++b) {
                    float4 v = *(const float4*)(sqi + 8 * b);
                    c[4 * b + 0] = 0.5f * (T_CUT - v.x);
                    c[4 * b + 1] = 0.5f * (T_CUT - v.y);
                    c[4 * b + 2] = 0.5f * (T_CUT - v.z);
                    c[4 * b + 3] = 0.5f * (T_CUT - v.w);
                }
            }

            const short8* bp  = (const short8*)(xb + (size_t)(sb + j0) * DIM);
            const float*  sqj = sq + sb + j0;

            #pragma unroll 2
            for (int jt = 0; jt < JSPAN; jt += 32) {
                short8 bfrag = bp[((jt + l31) << 1) | half];
                float  hsqj  = 0.5f * sqj[jt + l31];
                floatx16 d = __builtin_amdgcn_mfma_f32_32x32x16_bf16(
                        afrag, bfrag, c, 0, 0, 0);
                float m0 = fmaxf(fmaxf(d[0], d[1]),   fmaxf(d[2], d[3]));
                float m1 = fmaxf(fmaxf(d[4], d[5]),   fmaxf(d[6], d[7]));
                float m2 = fmaxf(fmaxf(d[8], d[9]),   fmaxf(d[10], d[11]));
                float m3 = fmaxf(fmaxf(d[12], d[13]), fmaxf(d[14], d[15]));
                float m  = fmaxf(fmaxf(m0, m1), fmaxf(m2, m3));

                if (__any(m > hsqj)) {    // rare (incl. forced diagonal d2=0)
                    const int j = j0 + jt + l31;
                    #pragma unroll 1
                    for (int r = 0; r < 16; ++r) {
                        if (d[r] > hsqj) {
                            const int i = i0 + (r & 3) + 8 * (r >> 2) + 4 * half;
                            const float* xi = xin + (size_t)(sb + i) * DIM;
                            const float* xj = xin + (size_t)(sb + j) * DIM;
                            float dot = 0.0f;
                            #pragma unroll
                            for (int dd = 0; dd < 16; ++dd)
                                dot = fmaf(xi[dd], xj[dd], dot);
                            float d2 = fmaxf(fmaf(-2.0f, dot,
                                    sq[sb + i] + sq[sb + j]), 0.0f);
                            if (d2 < T_CUT && cost[sb + i] > cost[sb + j]) {
                                float w = 2.0f * expf(-d2);
                                #pragma unroll
                                for (int dd = 0; dd < 16; ++dd)
                                    atomicAdd(&attr[(size_t)(sb + i) * DIM + dd],
                                              w * (xj[dd] - xi[dd]));
                            }
                        }
                    }
                }
            }
        }
        grid.sync();

        // ---- update phase -------------------------------------------------
        float* xout = (step == steps - 1) ? out : ((step & 1) ? xB : xA);
        const float* nzp = noise + (size_t)step * NSI * DIM;
        const int mix = (step % 25 == 0) ? 1 : 0;
        for (int t = gid; t < NSI * DIM; t += GSIZE) {
            int si = t >> 4, d = t & 15;
            int s  = si >> 12;
            int i  = si & (POP - 1);

            float a = attr[t];
            attr[t] = 0.0f;                       // ready for next step
            float xv = xin[t];
            float xn = xv + a + alpha * (nzp[t] - 0.5f) * 8.0f;
            xn = fminf(fmaxf(xn, -4.0f), 4.0f);

            int s_out = (mix && i >= POP / 2) ? ((s + 1) & (SPECIES - 1)) : s;
            int outsi = s_out * POP + i;
            size_t ot = (size_t)outsi * DIM + d;
            xout[ot] = xn;
            xb[ot]   = f2bf(xn);

            float s1t = seg16_sum(xn * xn);
            float ct  = seg16_sum(cospif(2.0f * xn));
            if (d == 0) {
                sq[outsi]   = s1t;
                cost[outsi] = 10.0f * DIM + s1t - 10.0f * ct;
            }
        }
        grid.sync();

        xin = xout;
        alpha *= 0.995f;
    }
}

extern "C" void kernel_launch(void* const* d_in, const int* in_sizes, int n_in,
                              void* d_out, int out_size, void* d_ws, size_t ws_size,
                              hipStream_t stream) {
    const float* x0    = (const float*)d_in[0];
    const float* noise = (const float*)d_in[1];
    int steps = in_sizes[1] / in_sizes[0];            // = 4
    float* out = (float*)d_out;

    float* f    = (float*)d_ws;
    float* xA   = f;                                  // NSI*DIM
    float* xB   = xA + (size_t)NSI * DIM;             // NSI*DIM
    float* attr = xB + (size_t)NSI * DIM;             // NSI*DIM
    float* sq   = attr + (size_t)NSI * DIM;           // NSI
    float* cost = sq + NSI;                           // NSI
    unsigned short* xb = (unsigned short*)(cost + NSI);

    void* args[] = {
        (void*)&x0, (void*)&noise, (void*)&steps, (void*)&out,
        (void*)&xA, (void*)&xB, (void*)&attr,
        (void*)&sq, (void*)&cost, (void*)&xb,
    };
    hipLaunchCooperativeKernel(reinterpret_cast<void*>(mega_kernel),
                               dim3(GRID), dim3(BLOCK), args, 0, stream);
}

// Round 5
// 147.538 us; speedup vs baseline: 4.4146x; 4.4146x over previous
//
#include <hip/hip_runtime.h>

// Firefly optimizer, round 5: one kernel per step (5 dispatches total).
// R4 post-mortem: cg::grid.sync() costs ~65us each on MI355X (spin + L2
// invalidate across 8 XCDs) -> cooperative fusion regressed 4x. Kernel
// boundaries are the cheap barrier (~12us); so minimize dispatch count to
// steps+1 by carrying attraction between steps as a COMPACT HOT LIST
// (~6 entries/step, P(d2<10)~8e-8) in block-private slots (no zero-init
// needed), and having each step kernel redundantly recompute the updated
// rows it needs (128 i-rows + 1024 j-rows) into LDS before the MFMA gate.
// Gate math unchanged from R3: D = g_bf16 + (T-sqi)/2, hot <=> D > sqj/2,
// exact-fp32 slow path recomputes rows via the same inlined function.

#define SPECIES 4
#define POP     4096
#define DIM     16
#define NSI     (SPECIES * POP)
#define T_CUT   10.0f
#define NBLK    512        // step-kernel grid: 4 species x 32 itiles x 4 jc
#define CAP_B   64         // hot-list entries per block
#define LCAP    128        // compacted list cap (expected ~6)
#define ITR     128        // i-rows per block
#define JSPAN   1024       // j-rows per block

typedef __attribute__((ext_vector_type(8)))  short short8;    // 8 bf16
typedef __attribute__((ext_vector_type(16))) float floatx16;  // MFMA C/D

__device__ __forceinline__ unsigned short f2bf(float f) {
    unsigned u = __float_as_uint(f);
    u += 0x7FFFu + ((u >> 16) & 1u);
    return (unsigned short)(u >> 16);
}

// Exact fp32 updated position of `row` at this step (post-mix indexing).
// Used by phase A (all needed rows) and the rare slow path -> identical ops.
__device__ __forceinline__ void compute_x16(
        const float* __restrict__ xprev, const float* __restrict__ nz,
        float alpha, int mix, int upd, int row,
        const int* __restrict__ lrow, const float* __restrict__ lvec, int nl,
        float v[16]) {
    int src = row;
    if (upd && mix) {
        int i = row & (POP - 1);
        if (i >= POP / 2)
            src = ((((row >> 12) + SPECIES - 1) & (SPECIES - 1)) << 12) | i;
    }
    const float* xp = xprev + (size_t)src * DIM;
    if (!upd) {
        #pragma unroll
        for (int d = 0; d < 16; ++d) v[d] = xp[d];
        return;
    }
    const float* np = nz + (size_t)src * DIM;
    float add[16];
    #pragma unroll
    for (int d = 0; d < 16; ++d) add[d] = 0.0f;
    for (int e = 0; e < nl; ++e) {        // nl ~ 6
        if (lrow[e] == src) {
            #pragma unroll
            for (int d = 0; d < 16; ++d) add[d] += lvec[e * 16 + d];
        }
    }
    #pragma unroll
    for (int d = 0; d < 16; ++d) {
        float xn = (xp[d] + add[d]) + alpha * (np[d] - 0.5f) * 8.0f;
        v[d] = fminf(fmaxf(xn, -4.0f), 4.0f);
    }
}

__global__ __launch_bounds__(256) void step_kernel(
        const float* __restrict__ xprev, const float* __restrict__ nz,
        float alpha, int mix, int upd,
        float* __restrict__ xcur,                       // materialize x_s
        const int* __restrict__ cin, const int* __restrict__ rin,
        const float* __restrict__ vin, int have_in,
        int* __restrict__ cout, int* __restrict__ rout,
        float* __restrict__ vout) {
    __shared__ unsigned short xb_i[ITR * DIM];          //  4 KB
    __shared__ unsigned short xb_j[JSPAN * DIM];        // 32 KB
    __shared__ float sq_i[ITR], cost_i[ITR];            //  1 KB
    __shared__ float sq_j[JSPAN], cost_j[JSPAN];        //  8 KB
    __shared__ int   lrow[LCAP];                        // 0.5 KB
    __shared__ float lvec[LCAP * 16];                   //  8 KB
    __shared__ int   nl_s, cnt_s;

    const int tid = threadIdx.x;
    const int b   = blockIdx.x;
    const int jc  = b & 3;
    const int it  = (b >> 2) & 31;
    const int sp  = b >> 7;
    const int sb  = sp * POP;
    const int i0  = it * ITR;
    const int j0  = jc * JSPAN;

    if (tid == 0) { nl_s = 0; cnt_s = 0; }
    __syncthreads();

    // ---- compact incoming hot list ----------------------------------------
    if (have_in) {
        for (int t = tid; t < NBLK; t += 256) {
            int c = cin[t];
            if (c > 0) {
                c = min(c, CAP_B);
                int base = atomicAdd(&nl_s, c);
                for (int e = 0; e < c; ++e) {
                    int slot = base + e;
                    if (slot < LCAP) {
                        lrow[slot] = rin[t * CAP_B + e];
                        for (int d = 0; d < 16; ++d)
                            lvec[slot * 16 + d] = vin[(t * CAP_B + e) * 16 + d];
                    }
                }
            }
        }
    }
    __syncthreads();
    const int nl = min(nl_s, LCAP);

    // ---- phase A: build x_s rows this block needs into LDS ----------------
    for (int r = tid; r < ITR + JSPAN; r += 256) {
        int row = (r < ITR) ? (sb + i0 + r) : (sb + j0 + (r - ITR));
        float v[16];
        compute_x16(xprev, nz, alpha, mix, upd, row, lrow, lvec, nl, v);
        float sqv = 0.0f, cv = 0.0f;
        #pragma unroll
        for (int d = 0; d < 16; ++d) {
            sqv = fmaf(v[d], v[d], sqv);
            cv += cospif(2.0f * v[d]);
        }
        float cost = 10.0f * DIM + sqv - 10.0f * cv;
        if (r < ITR) {
            #pragma unroll
            for (int d = 0; d < 16; ++d) xb_i[r * 16 + d] = f2bf(v[d]);
            sq_i[r] = sqv; cost_i[r] = cost;
            if (upd && jc == 0) {                // materialize x_s once
                float* xo = xcur + (size_t)row * DIM;
                #pragma unroll
                for (int d = 0; d < 16; ++d) xo[d] = v[d];
            }
        } else {
            int jj = r - ITR;
            #pragma unroll
            for (int d = 0; d < 16; ++d) xb_j[jj * 16 + d] = f2bf(v[d]);
            sq_j[jj] = sqv; cost_j[jj] = cost;
        }
    }
    __syncthreads();

    // ---- phase B: MFMA gate over 32x32 tiles ------------------------------
    const int lane = tid & 63, wave = tid >> 6;
    const int l31 = lane & 31, half = lane >> 5;
    const int iw0 = wave * 32;

    const short8* axi = (const short8*)xb_i;
    const short8* axj = (const short8*)xb_j;
    const short8 afrag = axi[((iw0 + l31) << 1) | half];

    floatx16 c;   // row r -> (r&3) + 8*(r>>2) + 4*half
    {
        const float* sp_ = sq_i + iw0 + 4 * half;
        #pragma unroll
        for (int bq = 0; bq < 4; ++bq)
            #pragma unroll
            for (int t2 = 0; t2 < 4; ++t2)
                c[4 * bq + t2] = 0.5f * (T_CUT - sp_[8 * bq + t2]);
    }

    for (int jt = 0; jt < JSPAN; jt += 32) {
        short8 bfrag = axj[((jt + l31) << 1) | half];
        float  hsqj  = 0.5f * sq_j[jt + l31];
        floatx16 d = __builtin_amdgcn_mfma_f32_32x32x16_bf16(afrag, bfrag, c,
                                                             0, 0, 0);
        float m0 = fmaxf(fmaxf(d[0], d[1]),   fmaxf(d[2], d[3]));
        float m1 = fmaxf(fmaxf(d[4], d[5]),   fmaxf(d[6], d[7]));
        float m2 = fmaxf(fmaxf(d[8], d[9]),   fmaxf(d[10], d[11]));
        float m3 = fmaxf(fmaxf(d[12], d[13]), fmaxf(d[14], d[15]));
        float m  = fmaxf(fmaxf(m0, m1), fmaxf(m2, m3));

        if (__any(m > hsqj)) {     // rare (incl. diagonal d2=0, cost-equal)
            const int jl = jt + l31;
            #pragma unroll 1
            for (int r = 0; r < 16; ++r) {
                if (d[r] > hsqj) {
                    const int il = iw0 + (r & 3) + 8 * (r >> 2) + 4 * half;
                    if (cost_i[il] > cost_j[jl]) {
                        float xi[16], xj[16];
                        compute_x16(xprev, nz, alpha, mix, upd,
                                    sb + i0 + il, lrow, lvec, nl, xi);
                        compute_x16(xprev, nz, alpha, mix, upd,
                                    sb + j0 + jl, lrow, lvec, nl, xj);
                        float dot = 0.0f;
                        #pragma unroll
                        for (int dd = 0; dd < 16; ++dd)
                            dot = fmaf(xi[dd], xj[dd], dot);
                        float d2 = fmaxf(fmaf(-2.0f, dot,
                                              sq_i[il] + sq_j[jl]), 0.0f);
                        if (d2 < T_CUT) {
                            float w = 2.0f * expf(-d2);
                            int slot = atomicAdd(&cnt_s, 1);
                            if (slot < CAP_B) {
                                int g = b * CAP_B + slot;
                                rout[g] = sb + i0 + il;
                                #pragma unroll
                                for (int dd = 0; dd < 16; ++dd)
                                    vout[g * 16 + dd] = w * (xj[dd] - xi[dd]);
                            }
                        }
                    }
                }
            }
        }
    }
    __syncthreads();
    if (tid == 0) cout[b] = min(cnt_s, CAP_B);   // unconditional: no pre-zero
}

// ---- final update -> d_out -------------------------------------------------
__global__ __launch_bounds__(256) void final_kernel(
        const float* __restrict__ xprev, const float* __restrict__ nz,
        float alpha, int mix,
        const int* __restrict__ cin, const int* __restrict__ rin,
        const float* __restrict__ vin,
        float* __restrict__ out) {
    __shared__ int   lrow[LCAP];
    __shared__ float lvec[LCAP * 16];
    __shared__ int   nl_s;
    const int tid = threadIdx.x;
    if (tid == 0) nl_s = 0;
    __syncthreads();
    for (int t = tid; t < NBLK; t += 256) {
        int c = cin[t];
        if (c > 0) {
            c = min(c, CAP_B);
            int base = atomicAdd(&nl_s, c);
            for (int e = 0; e < c; ++e) {
                int slot = base + e;
                if (slot < LCAP) {
                    lrow[slot] = rin[t * CAP_B + e];
                    for (int d = 0; d < 16; ++d)
                        lvec[slot * 16 + d] = vin[(t * CAP_B + e) * 16 + d];
                }
            }
        }
    }
    __syncthreads();
    const int nl = min(nl_s, LCAP);

    int row = blockIdx.x * 32 + (tid >> 3);      // 512 blocks x 32 rows
    int dq  = (tid & 7) * 2;                     // 8 threads/row, 2 dims each
    if (row < NSI) {
        float v[16];
        compute_x16(xprev, nz, alpha, mix, 1, row, lrow, lvec, nl, v);
        float2* o = (float2*)(out + (size_t)row * DIM + dq);
        *o = make_float2(v[dq], v[dq + 1]);
    }
}

extern "C" void kernel_launch(void* const* d_in, const int* in_sizes, int n_in,
                              void* d_out, int out_size, void* d_ws, size_t ws_size,
                              hipStream_t stream) {
    const float* x0    = (const float*)d_in[0];
    const float* noise = (const float*)d_in[1];
    const int steps = in_sizes[1] / in_sizes[0];      // = 4

    float* f     = (float*)d_ws;
    float* xA    = f;                                 // NSI*DIM
    float* xB    = xA + (size_t)NSI * DIM;            // NSI*DIM
    int*   cnt   = (int*)(xB + (size_t)NSI * DIM);    // 2*NBLK
    int*   lrows = cnt + 2 * NBLK;                    // 2*NBLK*CAP_B
    float* lvecs = (float*)(lrows + 2 * NBLK * CAP_B);// 2*NBLK*CAP_B*16

    const float* xp = x0;
    for (int s = 0; s < steps; ++s) {
        const int upd = (s > 0);
        const int li = (s - 1) & 1, lo = s & 1;
        float a = 0.1f;
        for (int k = 1; k < s; ++k) a *= 0.995f;      // alpha_{s-1}
        const int mix = (upd && ((s - 1) % 25 == 0)) ? 1 : 0;
        float* xc = (s & 1) ? xA : xB;
        step_kernel<<<NBLK, 256, 0, stream>>>(
            xp, upd ? noise + (size_t)(s - 1) * NSI * DIM : x0,
            upd ? a : 0.0f, mix, upd, xc,
            cnt + li * NBLK, lrows + li * NBLK * CAP_B,
            lvecs + (size_t)li * NBLK * CAP_B * 16, upd,
            cnt + lo * NBLK, lrows + lo * NBLK * CAP_B,
            lvecs + (size_t)lo * NBLK * CAP_B * 16);
        if (upd) xp = xc;
    }
    {
        const int li = (steps - 1) & 1;
        float a = 0.1f;
        for (int k = 1; k < steps; ++k) a *= 0.995f;  // alpha_{steps-1}
        const int mix = ((steps - 1) % 25 == 0) ? 1 : 0;
        final_kernel<<<NBLK, 256, 0, stream>>>(
            xp, noise + (size_t)(steps - 1) * NSI * DIM, a, mix,
            cnt + li * NBLK, lrows + li * NBLK * CAP_B,
            lvecs + (size_t)li * NBLK * CAP_B * 16,
            (float*)d_out);
    }
}